// Round 9
// baseline (234.552 us; speedup 1.0000x reference)
//
#include <hip/hip_runtime.h>

#define NDIM 4096
#define B_LG 256
#define B_SM 256
#define N_WID 128
#define R_LG 64
#define R_SM 16
#define BLOCK 512
#define MAXB 256           // bucket capacity per wid
#define PF 8               // float4 loads issued back-to-back (8 KB/wave in flight)
#define MAXM 4             // batches fused per pass (acc 16 VGPR, no spill)
#define OUT_SIZE (B_LG * R_LG + B_SM * R_SM)

typedef float floatv4 __attribute__((ext_vector_type(4)));

// d_ws ints: [0..128) cnt_l | [128..256) cnt_s | buckets
#define WS_CNT_L 0
#define WS_CNT_S 128
#define WS_BKT_L 256
#define WS_BKT_S (256 + N_WID * MAXB)

// ------------- kernel 1: bucket batches by wid + zero out -------------------
__global__ __launch_bounds__(BLOCK)
void setup_kernel(const int* __restrict__ wids_l,
                  const int* __restrict__ wids_s,
                  int* __restrict__ ws,
                  float* __restrict__ out)
{
    __shared__ int cl[N_WID], cs[N_WID];
    const int t = threadIdx.x;
    if (t < N_WID) { cl[t] = 0; cs[t] = 0; }
    __syncthreads();
    if (t < B_LG) {
        const int w = wids_l[t];
        const int s = atomicAdd(&cl[w], 1);
        ws[WS_BKT_L + w * MAXB + s] = t;
    } else if (t < B_LG + B_SM) {
        const int b = t - B_LG;
        const int w = wids_s[b];
        const int s = atomicAdd(&cs[w], 1);
        ws[WS_BKT_S + w * MAXB + s] = b;
    }
    __syncthreads();
    if (t < N_WID) { ws[WS_CNT_L + t] = cl[t]; ws[WS_CNT_S + t] = cs[t]; }
    for (int i = t; i < OUT_SIZE; i += BLOCK) out[i] = 0.0f;
}

// ------------- kernel 2: grouped chunk-GEMV, forced-MLP pipeline ------------
// One 512-thread block streams a 128 KB chunk of A[wid] once; each pipeline
// group issues ALL PF nontemporal loads before the first FMA consumes buf[0],
// so >=8 loads/wave are structurally in flight (progressive vmcnt drain).
// Partial dots combine across chunks via atomicAdd into zeroed out.
template<int R, int M, int DCH>
__device__ __forceinline__ void gemv_chunk(
    const float* __restrict__ x,      // x rows base for this class
    const float* __restrict__ Ab,     // A[wid]
    float* __restrict__ outb,         // out base for this class
    const int* __restrict__ batches,  // M batch indices (uniform scalar reads)
    int d0,                           // d offset of this chunk
    float* __restrict__ xs,           // LDS, >= M*DCH floats
    float* __restrict__ red)          // LDS [8][16][4]
{
    constexpr int LPR  = R / 4;         // lanes per A-row: 16 (R=64) or 4 (R=16)
    constexpr int ROWS = BLOCK / LPR;   // A-rows per float4-iter: 32 or 128
    constexpr int IT   = DCH / ROWS;    // 16 for both classes
    constexpr int NG   = IT / PF;       // 2 pipeline groups

    const int t = threadIdx.x;

    int rows[M];
#pragma unroll
    for (int m = 0; m < M; ++m) rows[m] = batches[m];  // uniform -> s_load

    __syncthreads();  // previous pass's xs reads finished
#pragma unroll
    for (int m = 0; m < M; ++m)
        for (int i = t; i < DCH / 4; i += BLOCK)
            reinterpret_cast<float4*>(xs + m * DCH)[i] =
                reinterpret_cast<const float4*>(x + (size_t)rows[m] * NDIM + d0)[i];
    __syncthreads();

    const int d_sub  = t / LPR;
    const int r_base = (t % LPR) * 4;
    const float* Abt = Ab + ((size_t)d0 + d_sub) * R + r_base;

    float acc[M][4];
#pragma unroll
    for (int m = 0; m < M; ++m)
#pragma unroll
        for (int j = 0; j < 4; ++j) acc[m][j] = 0.0f;

#pragma unroll
    for (int g = 0; g < NG; ++g) {
        floatv4 buf[PF];
#pragma unroll
        for (int p = 0; p < PF; ++p)
            buf[p] = __builtin_nontemporal_load(
                reinterpret_cast<const floatv4*>(Abt + (size_t)(g * PF + p) * ROWS * R));
#pragma unroll
        for (int p = 0; p < PF; ++p) {
            const int d = (g * PF + p) * ROWS + d_sub;
#pragma unroll
            for (int m = 0; m < M; ++m) {
                const float xv = xs[m * DCH + d];
                acc[m][0] = fmaf(xv, buf[p].x, acc[m][0]);
                acc[m][1] = fmaf(xv, buf[p].y, acc[m][1]);
                acc[m][2] = fmaf(xv, buf[p].z, acc[m][2]);
                acc[m][3] = fmaf(xv, buf[p].w, acc[m][3]);
            }
        }
    }

    // reduce: shuffle within wave, LDS across 8 waves, atomicAdd per chunk
    const int wave = t >> 6;
    const int lane = t & 63;
#pragma unroll
    for (int m = 0; m < M; ++m)
#pragma unroll
        for (int off = 32; off >= LPR; off >>= 1)
#pragma unroll
            for (int j = 0; j < 4; ++j)
                acc[m][j] += __shfl_down(acc[m][j], off, 64);

#pragma unroll
    for (int m = 0; m < M; ++m) {
        __syncthreads();
        if (lane < LPR)
#pragma unroll
            for (int j = 0; j < 4; ++j) red[(wave * 16 + lane) * 4 + j] = acc[m][j];
        __syncthreads();
        if (t < R) {
            const int rl = t / 4, j = t % 4;
            float v = 0.0f;
#pragma unroll
            for (int w = 0; w < 8; ++w) v += red[(w * 16 + rl) * 4 + j];
            atomicAdd(outb + (size_t)rows[m] * R + t, v);
        }
    }
}

template<int R, int DCH>
__device__ __forceinline__ void run_wid_chunk(
    const float* x, const float* Ab, float* outb,
    const int* bucket, int count, int d0,
    float* xs, float* red)
{
    for (int g = 0; g < count; g += MAXM) {
        const int Mi = min(MAXM, count - g);
        const int* b = bucket + g;
        if (Mi == 1)      gemv_chunk<R, 1, DCH>(x, Ab, outb, b, d0, xs, red);
        else if (Mi == 2) gemv_chunk<R, 2, DCH>(x, Ab, outb, b, d0, xs, red);
        else if (Mi == 3) gemv_chunk<R, 3, DCH>(x, Ab, outb, b, d0, xs, red);
        else              gemv_chunk<R, 4, DCH>(x, Ab, outb, b, d0, xs, red);
    }
}

// Grid: 1280 blocks, all 128 KB A-chunks.
// [0,1024): large wids, 8 chunks x 512 d-rows.  wid = blk & 127, chunk = blk >> 7.
// [1024,1280): small wids, 2 chunks x 2048 d-rows.
__global__ __launch_bounds__(BLOCK, 4)
void SequentialLoraA_kernel(const float* __restrict__ x,
                            const float* __restrict__ Al,
                            const float* __restrict__ As,
                            float* __restrict__ out,
                            const int* __restrict__ ws)
{
    __shared__ float xs[MAXM * 2048];    // 32 KB (large uses 4x512, small 4x2048)
    __shared__ float red[8 * 16 * 4];    // 2 KB

    const int blk = blockIdx.x;
    if (blk < 8 * N_WID) {
        const int wid = blk & (N_WID - 1);
        const int d0  = (blk >> 7) * 512;
        run_wid_chunk<R_LG, 512>(x,
                                 Al + (size_t)wid * NDIM * R_LG,
                                 out,
                                 ws + WS_BKT_L + wid * MAXB,
                                 ws[WS_CNT_L + wid], d0,
                                 xs, red);
    } else {
        const int b2  = blk - 8 * N_WID;
        const int wid = b2 & (N_WID - 1);
        const int d0  = (b2 >> 7) * 2048;
        run_wid_chunk<R_SM, 2048>(x + (size_t)B_LG * NDIM,
                                  As + (size_t)wid * NDIM * R_SM,
                                  out + (size_t)B_LG * R_LG,
                                  ws + WS_BKT_S + wid * MAXB,
                                  ws[WS_CNT_S + wid], d0,
                                  xs, red);
    }
}

extern "C" void kernel_launch(void* const* d_in, const int* in_sizes, int n_in,
                              void* d_out, int out_size, void* d_ws, size_t ws_size,
                              hipStream_t stream) {
    const float* x      = (const float*)d_in[0];
    const int*   wids_l = (const int*)d_in[1];
    const int*   wids_s = (const int*)d_in[2];
    const float* Al     = (const float*)d_in[3];
    const float* As     = (const float*)d_in[4];
    float* out = (float*)d_out;
    int*   ws  = (int*)d_ws;

    setup_kernel<<<1, BLOCK, 0, stream>>>(wids_l, wids_s, ws, out);
    SequentialLoraA_kernel<<<10 * N_WID, BLOCK, 0, stream>>>(x, Al, As, out, ws);
}

// Round 10
// 225.787 us; speedup vs baseline: 1.0388x; 1.0388x over previous
//
#include <hip/hip_runtime.h>

#define NDIM 4096
#define B_LG 256
#define B_SM 256
#define N_WID 128
#define R_LG 64
#define R_SM 16
#define BLOCK 256
#define MAXB 256           // bucket capacity per wid
#define PF 8               // float4 loads per pipeline stage (8 KB/wave in flight)
#define MAXM 4             // batches fused per pass over A
#define OUT_SIZE (B_LG * R_LG + B_SM * R_SM)

typedef float floatv4 __attribute__((ext_vector_type(4)));

// d_ws ints: [0..128) cnt_l | [128..256) cnt_s | buckets
#define WS_CNT_L 0
#define WS_CNT_S 128
#define WS_BKT_L 256
#define WS_BKT_S (256 + N_WID * MAXB)

// ------------- kernel 1: bucket batches by wid + zero out -------------------
__global__ __launch_bounds__(BLOCK)
void setup_kernel(const int* __restrict__ wids_l,
                  const int* __restrict__ wids_s,
                  int* __restrict__ ws,
                  float* __restrict__ out)
{
    __shared__ int cl[N_WID], cs[N_WID];
    const int t = threadIdx.x;
    if (t < N_WID) { cl[t] = 0; cs[t] = 0; }
    __syncthreads();
    {
        const int w = wids_l[t];
        const int s = atomicAdd(&cl[w], 1);
        ws[WS_BKT_L + w * MAXB + s] = t;
    }
    {
        const int w = wids_s[t];
        const int s = atomicAdd(&cs[w], 1);
        ws[WS_BKT_S + w * MAXB + s] = t;
    }
    __syncthreads();
    if (t < N_WID) { ws[WS_CNT_L + t] = cl[t]; ws[WS_CNT_S + t] = cs[t]; }
    for (int i = t; i < OUT_SIZE; i += BLOCK) out[i] = 0.0f;
}

// ------------- kernel 2: software-pipelined grouped chunk-GEMV --------------
// One 256-thread block streams a 256 KB chunk of A[wid] once. Ping-pong
// register pipeline: stage g+1's PF nt-loads are issued BEFORE the loop
// back-edge and consumed AFTER it -> the allocator must keep 8 float4s live
// across the branch; loads are serviced during the previous stage's FMAs.
// Partial dots combine across chunks via atomicAdd into zeroed out.
template<int R, int M, int DCH>
__device__ __forceinline__ void gemv_chunk(
    const float* __restrict__ x,      // x rows base for this class
    const float* __restrict__ Ab,     // A[wid]
    float* __restrict__ outb,         // out base for this class
    const int* __restrict__ batches,  // M batch indices (uniform scalar reads)
    int d0,                           // d offset of this chunk
    float* __restrict__ xs,           // LDS, >= M*DCH floats
    float* __restrict__ red)          // LDS [4][16][4]
{
    constexpr int LPR  = R / 4;         // lanes per A-row: 16 (R=64) or 4 (R=16)
    constexpr int ROWS = BLOCK / LPR;   // A-rows per float4-iter: 16 or 64
    constexpr int IT   = DCH / ROWS;    // 64 (large) or 32 (small)
    constexpr int NG   = IT / PF;       // 8 or 4 pipeline stages

    const int t = threadIdx.x;

    int rows[M];
#pragma unroll
    for (int m = 0; m < M; ++m) rows[m] = batches[m];  // uniform -> s_load

    __syncthreads();  // previous pass's xs reads finished
#pragma unroll
    for (int m = 0; m < M; ++m)
        for (int i = t; i < DCH / 4; i += BLOCK)
            reinterpret_cast<float4*>(xs + m * DCH)[i] =
                reinterpret_cast<const float4*>(x + (size_t)rows[m] * NDIM + d0)[i];
    __syncthreads();

    const int d_sub  = t / LPR;
    const int r_base = (t % LPR) * 4;
    const float* Abt = Ab + ((size_t)d0 + d_sub) * R + r_base;
    // ROWS*R == 1024 floats for both classes; stride between pipeline loads.

    float acc[M][4];
#pragma unroll
    for (int m = 0; m < M; ++m)
#pragma unroll
        for (int j = 0; j < 4; ++j) acc[m][j] = 0.0f;

    floatv4 buf[2][PF];
    // prologue: stage 0
#pragma unroll
    for (int p = 0; p < PF; ++p)
        buf[0][p] = __builtin_nontemporal_load(
            reinterpret_cast<const floatv4*>(Abt + (size_t)p * ROWS * R));

    // pipelined main loop: issue stage g+1, consume stage g, back-edge.
#pragma unroll 2
    for (int g = 0; g < NG - 1; ++g) {
        const int cb = g & 1;
#pragma unroll
        for (int p = 0; p < PF; ++p)
            buf[cb ^ 1][p] = __builtin_nontemporal_load(
                reinterpret_cast<const floatv4*>(Abt + (size_t)((g + 1) * PF + p) * ROWS * R));
#pragma unroll
        for (int p = 0; p < PF; ++p) {
            const int d = (g * PF + p) * ROWS + d_sub;
#pragma unroll
            for (int m = 0; m < M; ++m) {
                const float xv = xs[m * DCH + d];
                acc[m][0] = fmaf(xv, buf[cb][p].x, acc[m][0]);
                acc[m][1] = fmaf(xv, buf[cb][p].y, acc[m][1]);
                acc[m][2] = fmaf(xv, buf[cb][p].z, acc[m][2]);
                acc[m][3] = fmaf(xv, buf[cb][p].w, acc[m][3]);
            }
        }
    }
    // epilogue: consume last stage
    {
        const int cb = (NG - 1) & 1;
#pragma unroll
        for (int p = 0; p < PF; ++p) {
            const int d = ((NG - 1) * PF + p) * ROWS + d_sub;
#pragma unroll
            for (int m = 0; m < M; ++m) {
                const float xv = xs[m * DCH + d];
                acc[m][0] = fmaf(xv, buf[cb][p].x, acc[m][0]);
                acc[m][1] = fmaf(xv, buf[cb][p].y, acc[m][1]);
                acc[m][2] = fmaf(xv, buf[cb][p].z, acc[m][2]);
                acc[m][3] = fmaf(xv, buf[cb][p].w, acc[m][3]);
            }
        }
    }

    // reduce: shuffle within wave, LDS across 4 waves, atomicAdd per chunk
    const int wave = t >> 6;
    const int lane = t & 63;
#pragma unroll
    for (int m = 0; m < M; ++m)
#pragma unroll
        for (int off = 32; off >= LPR; off >>= 1)
#pragma unroll
            for (int j = 0; j < 4; ++j)
                acc[m][j] += __shfl_down(acc[m][j], off, 64);

#pragma unroll
    for (int m = 0; m < M; ++m) {
        __syncthreads();
        if (lane < LPR)
#pragma unroll
            for (int j = 0; j < 4; ++j) red[(wave * 16 + lane) * 4 + j] = acc[m][j];
        __syncthreads();
        if (t < R) {
            const int rl = t / 4, j = t % 4;
            float v = 0.0f;
#pragma unroll
            for (int w = 0; w < 4; ++w) v += red[(w * 16 + rl) * 4 + j];
            atomicAdd(outb + (size_t)rows[m] * R + t, v);
        }
    }
}

template<int R, int DCH>
__device__ __forceinline__ void run_wid_chunk(
    const float* x, const float* Ab, float* outb,
    const int* bucket, int count, int d0,
    float* xs, float* red)
{
    for (int g = 0; g < count; g += MAXM) {
        const int Mi = min(MAXM, count - g);
        const int* b = bucket + g;
        if (Mi == 1)      gemv_chunk<R, 1, DCH>(x, Ab, outb, b, d0, xs, red);
        else if (Mi == 2) gemv_chunk<R, 2, DCH>(x, Ab, outb, b, d0, xs, red);
        else if (Mi == 3) gemv_chunk<R, 3, DCH>(x, Ab, outb, b, d0, xs, red);
        else              gemv_chunk<R, 4, DCH>(x, Ab, outb, b, d0, xs, red);
    }
}

// Grid: 768 uniform 256 KB chunks.
// [0,512): large wids, 4 chunks x 1024 d-rows (wid = blk & 127, chunk = blk >> 7).
// [512,768): small wids, 2 chunks x 2048 d-rows.
__global__ __launch_bounds__(BLOCK, 4)
void SequentialLoraA_kernel(const float* __restrict__ x,
                            const float* __restrict__ Al,
                            const float* __restrict__ As,
                            float* __restrict__ out,
                            const int* __restrict__ ws)
{
    __shared__ float xs[MAXM * 2048];    // 32 KB (large uses 4x1024, small 4x2048)
    __shared__ float red[4 * 16 * 4];    // 1 KB

    const int blk = blockIdx.x;
    if (blk < 4 * N_WID) {
        const int wid = blk & (N_WID - 1);
        const int d0  = (blk >> 7) * 1024;
        run_wid_chunk<R_LG, 1024>(x,
                                  Al + (size_t)wid * NDIM * R_LG,
                                  out,
                                  ws + WS_BKT_L + wid * MAXB,
                                  ws[WS_CNT_L + wid], d0,
                                  xs, red);
    } else {
        const int b2  = blk - 4 * N_WID;
        const int wid = b2 & (N_WID - 1);
        const int d0  = (b2 >> 7) * 2048;
        run_wid_chunk<R_SM, 2048>(x + (size_t)B_LG * NDIM,
                                  As + (size_t)wid * NDIM * R_SM,
                                  out + (size_t)B_LG * R_LG,
                                  ws + WS_BKT_S + wid * MAXB,
                                  ws[WS_CNT_S + wid], d0,
                                  xs, red);
    }
}

extern "C" void kernel_launch(void* const* d_in, const int* in_sizes, int n_in,
                              void* d_out, int out_size, void* d_ws, size_t ws_size,
                              hipStream_t stream) {
    const float* x      = (const float*)d_in[0];
    const int*   wids_l = (const int*)d_in[1];
    const int*   wids_s = (const int*)d_in[2];
    const float* Al     = (const float*)d_in[3];
    const float* As     = (const float*)d_in[4];
    float* out = (float*)d_out;
    int*   ws  = (int*)d_ws;

    setup_kernel<<<1, BLOCK, 0, stream>>>(wids_l, wids_s, ws, out);
    SequentialLoraA_kernel<<<6 * N_WID, BLOCK, 0, stream>>>(x, Al, As, out, ws);
}